// Round 5
// baseline (272.485 us; speedup 1.0000x reference)
//
#include <hip/hip_runtime.h>

// CGConv x2 + masked readout. N=50000, E=800000, C=64.
// Per-node projections (MFMA) + CSR gather.
// R5: gather software pipeline -- LDS-staged edge indices, two 8-wide Ps load
// banks (16 loads in flight), flat edge iteration with scalar-guarded node
// flushes, one-node-ahead Pd/residual prefetch.
//
// ws layout: deg(200704) csum(256) scal(64) start(200704) cursor(200704)
// esrc(3.2M) h1b(6.4M) Pd(12.8M) Ps(12.8M) wt(64K)

#define NN 50000
#define EE 800000
#define N2 50176          // 49*1024, padded for scan
#define NTILE 782         // ceil(50000/64)
#define NWAVES 8192
#define EPW 98            // ceil(EE/NWAVES)

typedef short bf16x8 __attribute__((ext_vector_type(8)));
typedef float f32x4 __attribute__((ext_vector_type(4)));
typedef unsigned int uint4v __attribute__((ext_vector_type(4)));
typedef unsigned short u16x4 __attribute__((ext_vector_type(4)));
typedef int int4v __attribute__((ext_vector_type(4)));

#define LN2F 0.6931471805599453f
#define L2EF 1.4426950408889634f

#if __has_builtin(__builtin_amdgcn_exp2f)
#define EXP2(x) __builtin_amdgcn_exp2f(x)
#else
#define EXP2(x) __expf(LN2F * (x))
#endif
#if __has_builtin(__builtin_amdgcn_logf)
#define LOG2(x) __builtin_amdgcn_logf(x)
#else
#define LOG2(x) (L2EF * __logf(x))
#endif
#if __has_builtin(__builtin_amdgcn_rcpf)
#define RCPF(x) __builtin_amdgcn_rcpf(x)
#else
#define RCPF(x) (1.0f / (x))
#endif

__device__ __forceinline__ unsigned short f2b(float f) {
    unsigned int u = __builtin_bit_cast(unsigned int, f);
    return (unsigned short)((u + 0x7fffu + ((u >> 16) & 1u)) >> 16);
}
__device__ __forceinline__ float b2f(unsigned short b) {
    unsigned int u = ((unsigned int)b) << 16;
    return __builtin_bit_cast(float, u);
}
__device__ __forceinline__ float lo16f(unsigned int v) {
    return __builtin_bit_cast(float, v << 16);
}
__device__ __forceinline__ float hi16f(unsigned int v) {
    return __builtin_bit_cast(float, v & 0xFFFF0000u);
}
// per-edge message / ln2, with pre-scaled inputs: nF = -log2e*F, Sp = log2e*S
__device__ __forceinline__ float msg2(float nF, float Sp) {
    return RCPF(1.f + EXP2(nF)) * LOG2(1.f + EXP2(Sp));
}

// deg count + (blocks 0..127) weight prep.
__global__ __launch_bounds__(256) void k_deg_prep(const int* __restrict__ ei, int* __restrict__ deg,
                                                  const float* __restrict__ Wf1, const float* __restrict__ Ws1,
                                                  const float* __restrict__ Wf2, const float* __restrict__ Ws2,
                                                  unsigned short* __restrict__ wt) {
    int e = blockIdx.x * 256 + threadIdx.x;
    if (blockIdx.x < 128) {
        int i = e;               // 0..32767
        int layer = i >> 14;
        int j = i & 16383;
        int n = j >> 6, k = j & 63;
        const float* Wf = layer ? Wf2 : Wf1;
        const float* Ws = layer ? Ws2 : Ws1;
        float v;
        if (n < 64)       v = Wf[k * 64 + n];
        else if (n < 128) v = Ws[k * 64 + (n - 64)];
        else if (n < 192) v = Wf[(64 + k) * 64 + (n - 128)];
        else              v = Ws[(64 + k) * 64 + (n - 192)];
        int byte = ((n * 128 + k * 2) ^ ((n & 7) << 4)) + layer * 32768;
        *(unsigned short*)((char*)wt + byte) = f2b(v);
    }
    atomicAdd(&deg[ei[EE + e]], 1);
}

__global__ __launch_bounds__(1024) void k_scan1(const int* __restrict__ deg, int* __restrict__ start,
                                                int* __restrict__ csum) {
    __shared__ int s[1024];
    int t = threadIdx.x;
    int i = blockIdx.x * 1024 + t;
    int v = deg[i];
    s[t] = v; __syncthreads();
    for (int off = 1; off < 1024; off <<= 1) {
        int y = (t >= off) ? s[t - off] : 0; __syncthreads();
        s[t] += y; __syncthreads();
    }
    start[i] = s[t] - v;
    if (t == 1023) csum[blockIdx.x] = s[t];
}

__global__ __launch_bounds__(1024) void k_scan23(int* __restrict__ start, const int* __restrict__ csum,
                                                 int* __restrict__ cursor) {
    __shared__ int red[1024];
    int t = threadIdx.x;
    red[t] = (t < (int)blockIdx.x) ? csum[t] : 0;
    __syncthreads();
    for (int off = 512; off; off >>= 1) {
        if (t < off) red[t] += red[t + off];
        __syncthreads();
    }
    int base = red[0];
    int i = blockIdx.x * 1024 + t;
    int nv = start[i] + base;
    start[i] = nv;
    cursor[i] = nv;
}

__global__ __launch_bounds__(256) void k_fill(const int* __restrict__ ei, int* __restrict__ cursor,
                                              int* __restrict__ esrc) {
    int e = blockIdx.x * 256 + threadIdx.x;
    int dst = ei[EE + e];
    int p = atomicAdd(&cursor[dst], 1);
    esrc[p] = ei[e];
}

// P = H @ Wcat, 64 nodes x 256 cols per block, 4 waves.
// Output (per node, 64 dwords): dword c = [ -log2e*F_c (lo16) | log2e*S_c (hi16) ].
template <bool F32IN>
__global__ __launch_bounds__(256) void k_proj(const void* __restrict__ hin,
                                              const unsigned short* __restrict__ wt,
                                              const float* __restrict__ bfv, const float* __restrict__ bsv,
                                              unsigned short* __restrict__ Pd, unsigned short* __restrict__ Ps) {
    __shared__ unsigned short w_s[256 * 64];  // 32KB swizzled
    __shared__ unsigned short a_s[64 * 64];   // 8KB swizzled
    const int t = threadIdx.x;
    {
        const uint4v* src = (const uint4v*)wt;
        uint4v* dp = (uint4v*)w_s;
        #pragma unroll
        for (int i = 0; i < 8; ++i) dp[t + 256 * i] = src[t + 256 * i];
    }
    const int lane = t & 63, wid = t >> 6;
    const int cbase = lane & 15, q = lane >> 4;
    const int tile = blockIdx.x;

    #pragma unroll
    for (int i = 0; i < 2; ++i) {
        int ch = t + 256 * i;
        int r = ch >> 3, c8 = ch & 7;
        int node = tile * 64 + r;
        u16x4 lo = {0, 0, 0, 0}, hi = {0, 0, 0, 0};
        if (node < NN) {
            if (F32IN) {
                const float* xp = (const float*)hin + node * 64 + c8 * 8;
                f32x4 v0 = *(const f32x4*)xp;
                f32x4 v1 = *(const f32x4*)(xp + 4);
                lo[0] = f2b(v0[0]); lo[1] = f2b(v0[1]); lo[2] = f2b(v0[2]); lo[3] = f2b(v0[3]);
                hi[0] = f2b(v1[0]); hi[1] = f2b(v1[1]); hi[2] = f2b(v1[2]); hi[3] = f2b(v1[3]);
            } else {
                const unsigned short* hp = (const unsigned short*)hin + node * 64 + c8 * 8;
                lo = *(const u16x4*)hp;
                hi = *(const u16x4*)(hp + 4);
            }
        }
        int byte = (r * 128 + c8 * 16) ^ ((r & 7) << 4);
        *(u16x4*)((char*)a_s + byte) = lo;
        *(u16x4*)((char*)a_s + byte + 8) = hi;
    }
    __syncthreads();

    f32x4 acc[4][4];
    #pragma unroll
    for (int m = 0; m < 4; ++m)
        #pragma unroll
        for (int n = 0; n < 4; ++n) acc[m][n] = (f32x4){0.f, 0.f, 0.f, 0.f};

    #pragma unroll
    for (int ks = 0; ks < 2; ++ks) {
        bf16x8 a[4];
        #pragma unroll
        for (int m = 0; m < 4; ++m) {
            int mr = m * 16 + cbase;
            a[m] = *(const bf16x8*)((const char*)a_s + mr * 128 + ((ks * 64 + q * 16) ^ ((mr & 7) << 4)));
        }
        #pragma unroll
        for (int n = 0; n < 4; ++n) {
            int bn = wid * 64 + n * 16 + cbase;
            bf16x8 b = *(const bf16x8*)((const char*)w_s + bn * 128 + ((ks * 64 + q * 16) ^ ((bn & 7) << 4)));
            #pragma unroll
            for (int m = 0; m < 4; ++m)
                acc[m][n] = __builtin_amdgcn_mfma_f32_16x16x32_bf16(a[m], b, acc[m][n], 0, 0, 0);
        }
    }

    #pragma unroll
    for (int n = 0; n < 4; ++n) {
        int col = wid * 64 + n * 16 + cbase;
        unsigned short* outp;
        int oidx;
        float bias = 0.f, scale;
        if (col < 64)       { outp = Pd; oidx = 2 * col;             scale = -L2EF; }
        else if (col < 128) { outp = Pd; oidx = 2 * (col - 64) + 1;  scale =  L2EF; }
        else if (col < 192) { outp = Ps; oidx = 2 * (col - 128);     scale = -L2EF; bias = bfv[col - 128]; }
        else                { outp = Ps; oidx = 2 * (col - 192) + 1; scale =  L2EF; bias = bsv[col - 192]; }
        #pragma unroll
        for (int m = 0; m < 4; ++m) {
            int node = tile * 64 + m * 16 + q * 4;
            #pragma unroll
            for (int r = 0; r < 4; ++r)
                outp[(node + r) * 128 + oidx] = f2b((acc[m][n][r] + bias) * scale);
        }
    }
}

// Edge-balanced gather, software-pipelined. Wave w owns nodes with
// start[n] in [w*EPW,(w+1)*EPW). Edge indices staged in LDS; Ps row loads
// issued in two 8-wide banks (16 in flight); node flushes scalar-guarded.
template <int LAYER>
__global__ __launch_bounds__(256) void k_gather(const unsigned int* __restrict__ Pd,
                                                const unsigned int* __restrict__ Ps,
                                                const int* __restrict__ esrc, const int* __restrict__ start,
                                                const float* __restrict__ x,
                                                unsigned short* __restrict__ h1b,
                                                const float* __restrict__ surf, const float* __restrict__ Wlin,
                                                float* __restrict__ scal) {
    __shared__ int idx_s[4][256];
    const int lane = threadIdx.x & 63;
    const int wid = threadIdx.x >> 6;
    const int w = blockIdx.x * 4 + wid;

    int t0 = w * EPW, t1 = t0 + EPW;
    int lo = 0, hi = NN;
    while (lo < hi) { int mid = (lo + hi) >> 1; if (start[mid] < t0) lo = mid + 1; else hi = mid; }
    const int n0 = lo;
    hi = NN;
    while (lo < hi) { int mid = (lo + hi) >> 1; if (start[mid] < t1) lo = mid + 1; else hi = mid; }
    const int n1 = lo;

    const int e0 = __builtin_amdgcn_readfirstlane(start[n0]);
    const int cnt = __builtin_amdgcn_readfirstlane(start[n1]) - e0;
    int* idxp = idx_s[wid];
    for (int k = lane; k < cnt + 16; k += 64)
        idxp[k] = (k < cnt) ? esrc[e0 + k] : 0;

    float wlin = (LAYER == 2) ? Wlin[lane] : 0.f;
    float so = 0.f, ssum = 0.f;

    int n = n0;
    int nend = 0;
    float acc = 0.f, nfd = 0.f, sd = 0.f, xf = 0.f, xn = 0.f;
    unsigned int dvn = 0;
    if (n0 < n1) {
        unsigned int dv0 = Pd[n0 * 64 + lane];
        nfd = lo16f(dv0); sd = hi16f(dv0);
        xf = (LAYER == 1) ? x[n0 * 64 + lane] : b2f(h1b[n0 * 64 + lane]);
        int np = (n0 + 1 < NN) ? n0 + 1 : NN - 1;
        dvn = Pd[np * 64 + lane];
        xn = (LAYER == 1) ? x[np * 64 + lane] : b2f(h1b[np * 64 + lane]);
        nend = __builtin_amdgcn_readfirstlane(start[n0 + 1]) - e0;
    }

#define FLUSH() do {                                                          \
    if (LAYER == 1) {                                                         \
        h1b[n * 64 + lane] = f2b(xf + LN2F * acc);                            \
    } else {                                                                  \
        float v_ = (xf + LN2F * acc) * wlin;                                  \
        _Pragma("unroll")                                                     \
        for (int off_ = 32; off_; off_ >>= 1) v_ += __shfl_xor(v_, off_);     \
        if (lane == 0) { so += v_ * surf[n]; ssum += surf[n]; }               \
    }                                                                         \
    ++n; acc = 0.f;                                                           \
    nfd = lo16f(dvn); sd = hi16f(dvn); xf = xn;                               \
    { int np_ = (n + 1 < NN) ? n + 1 : NN - 1;                                \
      dvn = Pd[np_ * 64 + lane];                                              \
      xn = (LAYER == 1) ? x[np_ * 64 + lane] : b2f(h1b[np_ * 64 + lane]); }   \
    nend = __builtin_amdgcn_readfirstlane(start[n + 1]) - e0;                 \
} while (0)

#define LOADB(vv, kb_) do {                                                   \
    int4v j0_ = *(const int4v*)(idxp + (kb_));                                \
    int4v j1_ = *(const int4v*)(idxp + (kb_) + 4);                            \
    vv[0] = Ps[j0_[0] * 64 + lane]; vv[1] = Ps[j0_[1] * 64 + lane];           \
    vv[2] = Ps[j0_[2] * 64 + lane]; vv[3] = Ps[j0_[3] * 64 + lane];           \
    vv[4] = Ps[j1_[0] * 64 + lane]; vv[5] = Ps[j1_[1] * 64 + lane];           \
    vv[6] = Ps[j1_[2] * 64 + lane]; vv[7] = Ps[j1_[3] * 64 + lane];           \
} while (0)

#define COMP(vv, kb_) do {                                                    \
    _Pragma("unroll")                                                         \
    for (int i_ = 0; i_ < 8; ++i_) {                                          \
        int k_ = (kb_) + i_;                                                  \
        while (k_ == nend && n < n1) FLUSH();                                 \
        float m_ = msg2(nfd + lo16f(vv[i_]), sd + hi16f(vv[i_]));             \
        if (k_ < cnt) acc += m_;                                              \
    }                                                                         \
} while (0)

    if (cnt > 0) {
        unsigned int vA[8], vB[8];
        LOADB(vA, 0);
        int kb = 0;
        while (true) {
            LOADB(vB, kb + 8);
            COMP(vA, kb);
            kb += 8; if (kb >= cnt) break;
            LOADB(vA, kb + 8);
            COMP(vB, kb);
            kb += 8; if (kb >= cnt) break;
        }
    }
    while (n < n1) FLUSH();

#undef FLUSH
#undef LOADB
#undef COMP

    if (LAYER == 2) {
        __shared__ float ps[8];
        if (lane == 0) { ps[wid] = so; ps[4 + wid] = ssum; }
        __syncthreads();
        if (threadIdx.x == 0) {
            atomicAdd(scal + 0, ps[0] + ps[1] + ps[2] + ps[3]);
            atomicAdd(scal + 1, ps[4] + ps[5] + ps[6] + ps[7]);
        }
    }
}

__global__ void k_final(const float* __restrict__ scal, const float* __restrict__ blin,
                        float* __restrict__ out) {
    out[0] = (scal[0] + (float)NN * blin[0]) / scal[1];
}

extern "C" void kernel_launch(void* const* d_in, const int* in_sizes, int n_in,
                              void* d_out, int out_size, void* d_ws, size_t ws_size,
                              hipStream_t stream) {
    const float* x    = (const float*)d_in[0];
    const int*   ei   = (const int*)d_in[1];
    const float* surf = (const float*)d_in[2];
    const float* Wf1  = (const float*)d_in[3];
    const float* bf1  = (const float*)d_in[4];
    const float* Ws1  = (const float*)d_in[5];
    const float* bs1  = (const float*)d_in[6];
    const float* Wf2  = (const float*)d_in[7];
    const float* bf2  = (const float*)d_in[8];
    const float* Ws2  = (const float*)d_in[9];
    const float* bs2  = (const float*)d_in[10];
    const float* Wlin = (const float*)d_in[11];
    const float* blin = (const float*)d_in[12];

    unsigned char* ws = (unsigned char*)d_ws;
    int* deg    = (int*)(ws);                      // 200704 B (N2 ints)
    int* csum   = (int*)(ws + 200704);             // 256 B
    float* scal = (float*)(ws + 200960);           // 64 B
    int* start  = (int*)(ws + 201024);             // 200704 B
    int* cursor = (int*)(ws + 401728);             // 200704 B
    int* esrc   = (int*)(ws + 602432);             // 3,200,000 B
    unsigned short* h1b = (unsigned short*)(ws + 3802432);   // 6,406,144 B
    unsigned short* Pd  = (unsigned short*)(ws + 10208576);  // 12,812,288 B
    unsigned short* Ps  = (unsigned short*)(ws + 23020864);  // 12,812,288 B
    unsigned short* wt  = (unsigned short*)(ws + 35833152);  // 65,536 B

    hipMemsetAsync(d_ws, 0, 201024, stream);  // deg + csum + scal

    k_deg_prep<<<3125, 256, 0, stream>>>(ei, deg, Wf1, Ws1, Wf2, Ws2, wt);
    k_scan1<<<49, 1024, 0, stream>>>(deg, start, csum);
    k_scan23<<<49, 1024, 0, stream>>>(start, csum, cursor);
    k_fill<<<3125, 256, 0, stream>>>(ei, cursor, esrc);

    k_proj<true><<<NTILE, 256, 0, stream>>>(x, wt, bf1, bs1, Pd, Ps);
    k_gather<1><<<2048, 256, 0, stream>>>((const unsigned int*)Pd, (const unsigned int*)Ps,
                                          esrc, start, x, h1b, surf, Wlin, scal);
    k_proj<false><<<NTILE, 256, 0, stream>>>(h1b, wt + 16384, bf2, bs2, Pd, Ps);
    k_gather<2><<<2048, 256, 0, stream>>>((const unsigned int*)Pd, (const unsigned int*)Ps,
                                          esrc, start, x, h1b, surf, Wlin, scal);
    k_final<<<1, 1, 0, stream>>>(scal, blin, (float*)d_out);
}

// Round 7
// 254.245 us; speedup vs baseline: 1.0717x; 1.0717x over previous
//
#include <hip/hip_runtime.h>

// CGConv x2 + masked readout. N=50000, E=800000, C=64.
// Per-node projections (MFMA) + CSR gather.
// R6b: Ps table in fp8 e4m3 (packed [F8|S8] per chan, 128B/row) -- halves the
// random-read traffic that R3-R5 showed is the wall (125MB @ 1.4TB/s fixed).
// Pd stays bf16 (streamed; node-coherent error). Gather decodes v_cvt_f32_fp8.
//
// ws layout: deg(200704) csum(256) scal(64) start(200704) cursor(200704)
// esrc(3.2M) h1b(6.4M) Pd(12.8M) Ps(6.4M) wt(64K)

#define NN 50000
#define EE 800000
#define N2 50176          // 49*1024, padded for scan
#define NTILE 782         // ceil(50000/64)
#define NWAVES 8192
#define EPW 98            // ceil(EE/NWAVES)

typedef short bf16x8 __attribute__((ext_vector_type(8)));
typedef float f32x4 __attribute__((ext_vector_type(4)));
typedef unsigned int uint4v __attribute__((ext_vector_type(4)));
typedef unsigned short u16x4 __attribute__((ext_vector_type(4)));
typedef int int4v __attribute__((ext_vector_type(4)));

#define LN2F 0.6931471805599453f
#define L2EF 1.4426950408889634f

#if __has_builtin(__builtin_amdgcn_exp2f)
#define EXP2(x) __builtin_amdgcn_exp2f(x)
#else
#define EXP2(x) __expf(LN2F * (x))
#endif
#if __has_builtin(__builtin_amdgcn_logf)
#define LOG2(x) __builtin_amdgcn_logf(x)
#else
#define LOG2(x) (L2EF * __logf(x))
#endif
#if __has_builtin(__builtin_amdgcn_rcpf)
#define RCPF(x) __builtin_amdgcn_rcpf(x)
#else
#define RCPF(x) (1.0f / (x))
#endif

__device__ __forceinline__ unsigned short f2b(float f) {
    unsigned int u = __builtin_bit_cast(unsigned int, f);
    return (unsigned short)((u + 0x7fffu + ((u >> 16) & 1u)) >> 16);
}
__device__ __forceinline__ float b2f(unsigned short b) {
    unsigned int u = ((unsigned int)b) << 16;
    return __builtin_bit_cast(float, u);
}
__device__ __forceinline__ float lo16f(unsigned int v) {
    return __builtin_bit_cast(float, v << 16);
}
__device__ __forceinline__ float hi16f(unsigned int v) {
    return __builtin_bit_cast(float, v & 0xFFFF0000u);
}

// fp8 e4m3 encode (RNE via HW pack) / decode
__device__ __forceinline__ unsigned char f2fp8(float f) {
#if __has_builtin(__builtin_amdgcn_cvt_pk_fp8_f32)
    return (unsigned char)(__builtin_amdgcn_cvt_pk_fp8_f32(f, f, 0, false) & 0xff);
#else
    float a = fabsf(f); if (a > 448.f) a = 448.f;
    int e2; float m = frexpf(a, &e2);            // a = m * 2^e2, m in [0.5,1)
    int E = e2 + 6;                               // biased exp (e4m3 bias 7, normal 1.m)
    unsigned char r;
    if (a < 0.001953125f) {
        r = (unsigned char)(a * 512.f + 0.5f);
    } else {
        int mant = (int)(m * 16.f + 0.5f) - 8;    // m in [0.5,1) -> 1.mmm
        if (mant == 8) { mant = 0; ++E; }
        if (E > 15) { E = 15; mant = 7; }
        r = (unsigned char)((E << 3) | mant);
    }
    return r | (f < 0.f ? 0x80 : 0);
#endif
}
__device__ __forceinline__ float fp8lo(unsigned int v) {
#if __has_builtin(__builtin_amdgcn_cvt_f32_fp8)
    return __builtin_amdgcn_cvt_f32_fp8(v, 0);
#else
    unsigned b = v & 0xff;
    unsigned s = b >> 7, e = (b >> 3) & 15, mn = b & 7;
    float mag = e ? __builtin_ldexpf(1.f + mn * 0.125f, (int)e - 7)
                  : __builtin_ldexpf((float)mn, -9);
    return s ? -mag : mag;
#endif
}
__device__ __forceinline__ float fp8hi(unsigned int v) {
#if __has_builtin(__builtin_amdgcn_cvt_f32_fp8)
    return __builtin_amdgcn_cvt_f32_fp8(v, 1);
#else
    return fp8lo(v >> 8);
#endif
}

// per-edge message / ln2, with pre-scaled inputs: nF = -log2e*F, Sp = log2e*S
__device__ __forceinline__ float msg2(float nF, float Sp) {
    return RCPF(1.f + EXP2(nF)) * LOG2(1.f + EXP2(Sp));
}

// deg count + (blocks 0..127) weight prep.
__global__ __launch_bounds__(256) void k_deg_prep(const int* __restrict__ ei, int* __restrict__ deg,
                                                  const float* __restrict__ Wf1, const float* __restrict__ Ws1,
                                                  const float* __restrict__ Wf2, const float* __restrict__ Ws2,
                                                  unsigned short* __restrict__ wt) {
    int e = blockIdx.x * 256 + threadIdx.x;
    if (blockIdx.x < 128) {
        int i = e;               // 0..32767
        int layer = i >> 14;
        int j = i & 16383;
        int n = j >> 6, k = j & 63;
        const float* Wf = layer ? Wf2 : Wf1;
        const float* Ws = layer ? Ws2 : Ws1;
        float v;
        if (n < 64)       v = Wf[k * 64 + n];
        else if (n < 128) v = Ws[k * 64 + (n - 64)];
        else if (n < 192) v = Wf[(64 + k) * 64 + (n - 128)];
        else              v = Ws[(64 + k) * 64 + (n - 192)];
        int byte = ((n * 128 + k * 2) ^ ((n & 7) << 4)) + layer * 32768;
        *(unsigned short*)((char*)wt + byte) = f2b(v);
    }
    atomicAdd(&deg[ei[EE + e]], 1);
}

__global__ __launch_bounds__(1024) void k_scan1(const int* __restrict__ deg, int* __restrict__ start,
                                                int* __restrict__ csum) {
    __shared__ int s[1024];
    int t = threadIdx.x;
    int i = blockIdx.x * 1024 + t;
    int v = deg[i];
    s[t] = v; __syncthreads();
    for (int off = 1; off < 1024; off <<= 1) {
        int y = (t >= off) ? s[t - off] : 0; __syncthreads();
        s[t] += y; __syncthreads();
    }
    start[i] = s[t] - v;
    if (t == 1023) csum[blockIdx.x] = s[t];
}

__global__ __launch_bounds__(1024) void k_scan23(int* __restrict__ start, const int* __restrict__ csum,
                                                 int* __restrict__ cursor) {
    __shared__ int red[1024];
    int t = threadIdx.x;
    red[t] = (t < (int)blockIdx.x) ? csum[t] : 0;
    __syncthreads();
    for (int off = 512; off; off >>= 1) {
        if (t < off) red[t] += red[t + off];
        __syncthreads();
    }
    int base = red[0];
    int i = blockIdx.x * 1024 + t;
    int nv = start[i] + base;
    start[i] = nv;
    cursor[i] = nv;
}

__global__ __launch_bounds__(256) void k_fill(const int* __restrict__ ei, int* __restrict__ cursor,
                                              int* __restrict__ esrc) {
    int e = blockIdx.x * 256 + threadIdx.x;
    int dst = ei[EE + e];
    int p = atomicAdd(&cursor[dst], 1);
    esrc[p] = ei[e];
}

// P = H @ Wcat, 64 nodes x 256 cols per block, 4 waves.
// Pd (per node, 64 dwords): dword c = [ -log2e*F_c (lo16 bf16) | log2e*S_c (hi16 bf16) ].
// Ps (per node, 64 ushorts): ushort c = [ fp8(-log2e*(F_c+bf)) | fp8(log2e*(S_c+bs)) ].
template <bool F32IN>
__global__ __launch_bounds__(256) void k_proj(const void* __restrict__ hin,
                                              const unsigned short* __restrict__ wt,
                                              const float* __restrict__ bfv, const float* __restrict__ bsv,
                                              unsigned short* __restrict__ Pd, unsigned char* __restrict__ Ps) {
    __shared__ unsigned short w_s[256 * 64];  // 32KB swizzled
    __shared__ unsigned short a_s[64 * 64];   // 8KB swizzled
    const int t = threadIdx.x;
    {
        const uint4v* src = (const uint4v*)wt;
        uint4v* dp = (uint4v*)w_s;
        #pragma unroll
        for (int i = 0; i < 8; ++i) dp[t + 256 * i] = src[t + 256 * i];
    }
    const int lane = t & 63, wid = t >> 6;
    const int cbase = lane & 15, q = lane >> 4;
    const int tile = blockIdx.x;

    #pragma unroll
    for (int i = 0; i < 2; ++i) {
        int ch = t + 256 * i;
        int r = ch >> 3, c8 = ch & 7;
        int node = tile * 64 + r;
        u16x4 lo = {0, 0, 0, 0}, hi = {0, 0, 0, 0};
        if (node < NN) {
            if (F32IN) {
                const float* xp = (const float*)hin + node * 64 + c8 * 8;
                f32x4 v0 = *(const f32x4*)xp;
                f32x4 v1 = *(const f32x4*)(xp + 4);
                lo[0] = f2b(v0[0]); lo[1] = f2b(v0[1]); lo[2] = f2b(v0[2]); lo[3] = f2b(v0[3]);
                hi[0] = f2b(v1[0]); hi[1] = f2b(v1[1]); hi[2] = f2b(v1[2]); hi[3] = f2b(v1[3]);
            } else {
                const unsigned short* hp = (const unsigned short*)hin + node * 64 + c8 * 8;
                lo = *(const u16x4*)hp;
                hi = *(const u16x4*)(hp + 4);
            }
        }
        int byte = (r * 128 + c8 * 16) ^ ((r & 7) << 4);
        *(u16x4*)((char*)a_s + byte) = lo;
        *(u16x4*)((char*)a_s + byte + 8) = hi;
    }
    __syncthreads();

    f32x4 acc[4][4];
    #pragma unroll
    for (int m = 0; m < 4; ++m)
        #pragma unroll
        for (int n = 0; n < 4; ++n) acc[m][n] = (f32x4){0.f, 0.f, 0.f, 0.f};

    #pragma unroll
    for (int ks = 0; ks < 2; ++ks) {
        bf16x8 a[4];
        #pragma unroll
        for (int m = 0; m < 4; ++m) {
            int mr = m * 16 + cbase;
            a[m] = *(const bf16x8*)((const char*)a_s + mr * 128 + ((ks * 64 + q * 16) ^ ((mr & 7) << 4)));
        }
        #pragma unroll
        for (int n = 0; n < 4; ++n) {
            int bn = wid * 64 + n * 16 + cbase;
            bf16x8 b = *(const bf16x8*)((const char*)w_s + bn * 128 + ((ks * 64 + q * 16) ^ ((bn & 7) << 4)));
            #pragma unroll
            for (int m = 0; m < 4; ++m)
                acc[m][n] = __builtin_amdgcn_mfma_f32_16x16x32_bf16(a[m], b, acc[m][n], 0, 0, 0);
        }
    }

    #pragma unroll
    for (int n = 0; n < 4; ++n) {
        int col = wid * 64 + n * 16 + cbase;
        if (col < 128) {
            int oidx = (col < 64) ? 2 * col : 2 * (col - 64) + 1;
            float scale = (col < 64) ? -L2EF : L2EF;
            #pragma unroll
            for (int m = 0; m < 4; ++m) {
                int node = tile * 64 + m * 16 + q * 4;
                #pragma unroll
                for (int r = 0; r < 4; ++r)
                    Pd[(node + r) * 128 + oidx] = f2b(acc[m][n][r] * scale);
            }
        } else {
            float bias, scale; int boff;
            if (col < 192) { scale = -L2EF; bias = bfv[col - 128]; boff = 2 * (col - 128); }
            else           { scale =  L2EF; bias = bsv[col - 192]; boff = 2 * (col - 192) + 1; }
            #pragma unroll
            for (int m = 0; m < 4; ++m) {
                int node = tile * 64 + m * 16 + q * 4;
                #pragma unroll
                for (int r = 0; r < 4; ++r)
                    Ps[(node + r) * 128 + boff] = f2fp8((acc[m][n][r] + bias) * scale);
            }
        }
    }
}

// Edge-balanced gather, software-pipelined (R5 structure), fp8 Ps rows (128B).
template <int LAYER>
__global__ __launch_bounds__(256) void k_gather(const unsigned int* __restrict__ Pd,
                                                const unsigned short* __restrict__ Ps,
                                                const int* __restrict__ esrc, const int* __restrict__ start,
                                                const float* __restrict__ x,
                                                unsigned short* __restrict__ h1b,
                                                const float* __restrict__ surf, const float* __restrict__ Wlin,
                                                float* __restrict__ scal) {
    __shared__ int idx_s[4][256];
    const int lane = threadIdx.x & 63;
    const int wid = threadIdx.x >> 6;
    const int w = blockIdx.x * 4 + wid;

    int t0 = w * EPW, t1 = t0 + EPW;
    int lo = 0, hi = NN;
    while (lo < hi) { int mid = (lo + hi) >> 1; if (start[mid] < t0) lo = mid + 1; else hi = mid; }
    const int n0 = lo;
    hi = NN;
    while (lo < hi) { int mid = (lo + hi) >> 1; if (start[mid] < t1) lo = mid + 1; else hi = mid; }
    const int n1 = lo;

    const int e0 = __builtin_amdgcn_readfirstlane(start[n0]);
    const int cnt = __builtin_amdgcn_readfirstlane(start[n1]) - e0;
    int* idxp = idx_s[wid];
    for (int k = lane; k < cnt + 16; k += 64)
        idxp[k] = (k < cnt) ? esrc[e0 + k] : 0;

    float wlin = (LAYER == 2) ? Wlin[lane] : 0.f;
    float so = 0.f, ssum = 0.f;

    int n = n0;
    int nend = 0;
    float acc = 0.f, nfd = 0.f, sd = 0.f, xf = 0.f, xn = 0.f;
    unsigned int dvn = 0;
    if (n0 < n1) {
        unsigned int dv0 = Pd[n0 * 64 + lane];
        nfd = lo16f(dv0); sd = hi16f(dv0);
        xf = (LAYER == 1) ? x[n0 * 64 + lane] : b2f(h1b[n0 * 64 + lane]);
        int np = (n0 + 1 < NN) ? n0 + 1 : NN - 1;
        dvn = Pd[np * 64 + lane];
        xn = (LAYER == 1) ? x[np * 64 + lane] : b2f(h1b[np * 64 + lane]);
        nend = __builtin_amdgcn_readfirstlane(start[n0 + 1]) - e0;
    }

#define FLUSH() do {                                                          \
    if (LAYER == 1) {                                                         \
        h1b[n * 64 + lane] = f2b(xf + LN2F * acc);                            \
    } else {                                                                  \
        float v_ = (xf + LN2F * acc) * wlin;                                  \
        _Pragma("unroll")                                                     \
        for (int off_ = 32; off_; off_ >>= 1) v_ += __shfl_xor(v_, off_);     \
        if (lane == 0) { so += v_ * surf[n]; ssum += surf[n]; }               \
    }                                                                         \
    ++n; acc = 0.f;                                                           \
    nfd = lo16f(dvn); sd = hi16f(dvn); xf = xn;                               \
    { int np_ = (n + 1 < NN) ? n + 1 : NN - 1;                                \
      dvn = Pd[np_ * 64 + lane];                                              \
      xn = (LAYER == 1) ? x[np_ * 64 + lane] : b2f(h1b[np_ * 64 + lane]); }   \
    nend = __builtin_amdgcn_readfirstlane(start[n + 1]) - e0;                 \
} while (0)

#define LOADB(vv, kb_) do {                                                   \
    int4v j0_ = *(const int4v*)(idxp + (kb_));                                \
    int4v j1_ = *(const int4v*)(idxp + (kb_) + 4);                            \
    vv[0] = Ps[j0_[0] * 64 + lane]; vv[1] = Ps[j0_[1] * 64 + lane];           \
    vv[2] = Ps[j0_[2] * 64 + lane]; vv[3] = Ps[j0_[3] * 64 + lane];           \
    vv[4] = Ps[j1_[0] * 64 + lane]; vv[5] = Ps[j1_[1] * 64 + lane];           \
    vv[6] = Ps[j1_[2] * 64 + lane]; vv[7] = Ps[j1_[3] * 64 + lane];           \
} while (0)

#define COMP(vv, kb_) do {                                                    \
    _Pragma("unroll")                                                         \
    for (int i_ = 0; i_ < 8; ++i_) {                                          \
        int k_ = (kb_) + i_;                                                  \
        while (k_ == nend && n < n1) FLUSH();                                 \
        float m_ = msg2(nfd + fp8lo(vv[i_]), sd + fp8hi(vv[i_]));             \
        if (k_ < cnt) acc += m_;                                              \
    }                                                                         \
} while (0)

    if (cnt > 0) {
        unsigned int vA[8], vB[8];
        LOADB(vA, 0);
        int kb = 0;
        while (true) {
            LOADB(vB, kb + 8);
            COMP(vA, kb);
            kb += 8; if (kb >= cnt) break;
            LOADB(vA, kb + 8);
            COMP(vB, kb);
            kb += 8; if (kb >= cnt) break;
        }
    }
    while (n < n1) FLUSH();

#undef FLUSH
#undef LOADB
#undef COMP

    if (LAYER == 2) {
        __shared__ float ps[8];
        if (lane == 0) { ps[wid] = so; ps[4 + wid] = ssum; }
        __syncthreads();
        if (threadIdx.x == 0) {
            atomicAdd(scal + 0, ps[0] + ps[1] + ps[2] + ps[3]);
            atomicAdd(scal + 1, ps[4] + ps[5] + ps[6] + ps[7]);
        }
    }
}

__global__ void k_final(const float* __restrict__ scal, const float* __restrict__ blin,
                        float* __restrict__ out) {
    out[0] = (scal[0] + (float)NN * blin[0]) / scal[1];
}

extern "C" void kernel_launch(void* const* d_in, const int* in_sizes, int n_in,
                              void* d_out, int out_size, void* d_ws, size_t ws_size,
                              hipStream_t stream) {
    const float* x    = (const float*)d_in[0];
    const int*   ei   = (const int*)d_in[1];
    const float* surf = (const float*)d_in[2];
    const float* Wf1  = (const float*)d_in[3];
    const float* bf1  = (const float*)d_in[4];
    const float* Ws1  = (const float*)d_in[5];
    const float* bs1  = (const float*)d_in[6];
    const float* Wf2  = (const float*)d_in[7];
    const float* bf2  = (const float*)d_in[8];
    const float* Ws2  = (const float*)d_in[9];
    const float* bs2  = (const float*)d_in[10];
    const float* Wlin = (const float*)d_in[11];
    const float* blin = (const float*)d_in[12];

    unsigned char* ws = (unsigned char*)d_ws;
    int* deg    = (int*)(ws);                      // 200704 B (N2 ints)
    int* csum   = (int*)(ws + 200704);             // 256 B
    float* scal = (float*)(ws + 200960);           // 64 B
    int* start  = (int*)(ws + 201024);             // 200704 B
    int* cursor = (int*)(ws + 401728);             // 200704 B
    int* esrc   = (int*)(ws + 602432);             // 3,200,000 B
    unsigned short* h1b = (unsigned short*)(ws + 3802432);   // 6,406,144 B
    unsigned short* Pd  = (unsigned short*)(ws + 10208576);  // 12,812,288 B
    unsigned char*  Ps  = (unsigned char*)(ws + 23020864);   // 6,406,144 B (fp8)
    unsigned short* wt  = (unsigned short*)(ws + 35833152);  // 65,536 B

    hipMemsetAsync(d_ws, 0, 201024, stream);  // deg + csum + scal

    k_deg_prep<<<3125, 256, 0, stream>>>(ei, deg, Wf1, Ws1, Wf2, Ws2, wt);
    k_scan1<<<49, 1024, 0, stream>>>(deg, start, csum);
    k_scan23<<<49, 1024, 0, stream>>>(start, csum, cursor);
    k_fill<<<3125, 256, 0, stream>>>(ei, cursor, esrc);

    k_proj<true><<<NTILE, 256, 0, stream>>>(x, wt, bf1, bs1, Pd, Ps);
    k_gather<1><<<2048, 256, 0, stream>>>((const unsigned int*)Pd, (const unsigned short*)Ps,
                                          esrc, start, x, h1b, surf, Wlin, scal);
    k_proj<false><<<NTILE, 256, 0, stream>>>(h1b, wt + 16384, bf2, bs2, Pd, Ps);
    k_gather<2><<<2048, 256, 0, stream>>>((const unsigned int*)Pd, (const unsigned short*)Ps,
                                          esrc, start, x, h1b, surf, Wlin, scal);
    k_final<<<1, 1, 0, stream>>>(scal, blin, (float*)d_out);
}